// Round 2
// baseline (248.210 us; speedup 1.0000x reference)
//
#include <hip/hip_runtime.h>
#include <hip/hip_bf16.h>

#define N_TOT 65536
#define M_TOT 32768

typedef __bf16 bf16x8 __attribute__((ext_vector_type(8)));
typedef float  f32x4  __attribute__((ext_vector_type(4)));
typedef bf16x8 bf16x8_a __attribute__((may_alias));
typedef uint2  uint2_a  __attribute__((may_alias));

__device__ __forceinline__ float prelu_f(float x, float a) { return x >= 0.f ? x : a * x; }
// swizzle: uniform bank spread for BOTH stage-2 writes (row=4*j15+c) and
// stage-3 reads (row=16t+j15). XORs LDS 16B-slot index with ((row^(row>>3))&7).
__device__ __forceinline__ int swzf(int row) { return ((row ^ (row >> 3)) & 7) << 4; }

__device__ __forceinline__ bf16x8 cvt8(f32x4 a, f32x4 b) {
    bf16x8 v;
    v[0] = (__bf16)a[0]; v[1] = (__bf16)a[1]; v[2] = (__bf16)a[2]; v[3] = (__bf16)a[3];
    v[4] = (__bf16)b[0]; v[5] = (__bf16)b[1]; v[6] = (__bf16)b[2]; v[7] = (__bf16)b[3];
    return v;
}

// d_ws layout (bf16): [0,8192) Wm_t[64][128]; [8192,40960) Wms_t[256][128];
// [40960,49152) Wsa_t[64][128].  W*_t[n][k] = W[k][n].
__global__ void prep_weights(const float* __restrict__ Wm,
                             const float* __restrict__ Wms,
                             const float* __restrict__ Wsa,
                             __hip_bfloat16* __restrict__ ws)
{
    int t = blockIdx.x * blockDim.x + threadIdx.x;
    if (t < 8192) {
        int n = t >> 7, k = t & 127;
        ws[t] = __float2bfloat16(Wm[k * 64 + n]);
    } else if (t < 40960) {
        int u = t - 8192; int n = u >> 7, k = u & 127;
        ws[t] = __float2bfloat16(Wms[k * 256 + n]);
    } else if (t < 49152) {
        int u = t - 40960; int n = u >> 7, k = u & 127;
        ws[t] = __float2bfloat16(Wsa[k * 64 + n]);
    }
}

// One wave = 16 nodes, fused stage1/2/3. s' exchanged via 8KB/wave LDS tile,
// ans exchanged via 4-lane XOR shuffles (no LDS). Swapped MFMA: D = W^T X^T.
__global__ __launch_bounds__(256, 4) void encoder_fused(
    const float* __restrict__ last,
    const float* __restrict__ sample,
    const int* __restrict__ child_l,
    const int* __restrict__ child_r,
    const int* __restrict__ child_s,
    const __bf16* __restrict__ wt,
    const float* __restrict__ b_merge, const float* __restrict__ a_merge_p,
    const float* __restrict__ b_ms,    const float* __restrict__ a_ms_p,
    const float* __restrict__ b_msamp, const float* __restrict__ a_msamp_p,
    float* __restrict__ out)
{
    __shared__ char lds_raw[4][8192];       // 32KB/block -> 4-5 blocks/CU
    const int tid  = threadIdx.x;
    const int lane = tid & 63;
    const int wid  = tid >> 6;
    char* Y = &lds_raw[wid][0];             // wave-private [64 rows][128B]

    const int group  = blockIdx.x * 4 + wid;
    const int b      = group >> 11;
    const int m_base = (group & 2047) << 4;

    const int g   = lane >> 4;
    const int j15 = lane & 15;
    const int nl  = j15 >> 2;               // node-local (for stage1/3 rows)
    const int c   = j15 & 3;

    const float a_merge = *a_merge_p;
    const float a_ms    = *a_ms_p;
    const float a_msamp = *a_msamp_p;

    const __bf16* Wm_t  = wt;
    const __bf16* Wms_t = wt + 8192;
    const __bf16* Wsa_t = wt + 40960;

    // ---- index loads (all upfront) ----
    int cl[4], cr[4];
#pragma unroll
    for (int t = 0; t < 4; ++t) {
        cl[t] = child_l[m_base + t * 4 + nl];
        cr[t] = child_r[m_base + t * 4 + nl];
    }
    const int cs = child_s[m_base + j15];

    // ---- stage-2 sample loads (issue early) ----
    const float* ssrc = sample + ((size_t)(b * N_TOT + cs)) * 128;
    f32x4 sr[8];
#pragma unroll
    for (int kk = 0; kk < 4; ++kk) {
        sr[2 * kk]     = *(const f32x4*)(ssrc + kk * 32 + g * 8);
        sr[2 * kk + 1] = *(const f32x4*)(ssrc + kk * 32 + g * 8 + 4);
    }

    // ---- t=0 gather issue (in flight during stage-2 compute) ----
    f32x4 gr[2][8];
    {
        const float* lsrc = last + ((size_t)((b * N_TOT + cl[0]) * 4 + c)) * 64;
        const float* rsrc = last + ((size_t)((b * N_TOT + cr[0]) * 4 + c)) * 64;
#pragma unroll
        for (int kk = 0; kk < 4; ++kk) {
            const float* src = (kk < 2 ? lsrc + kk * 32 : rsrc + (kk - 2) * 32) + g * 8;
            gr[0][2 * kk]     = *(const f32x4*)(src);
            gr[0][2 * kk + 1] = *(const f32x4*)(src + 4);
        }
    }

    // ---- stage 2: s' = prelu(s @ W_ms + b_ms) -> LDS ----
    bf16x8 sf[4];
#pragma unroll
    for (int kk = 0; kk < 4; ++kk) sf[kk] = cvt8(sr[2 * kk], sr[2 * kk + 1]);
#pragma unroll
    for (int n2 = 0; n2 < 16; ++n2) {
        f32x4 acc = {0.f, 0.f, 0.f, 0.f};
#pragma unroll
        for (int kk = 0; kk < 4; ++kk) {
            bf16x8 w = *(const bf16x8*)(Wms_t + (n2 * 16 + j15) * 128 + kk * 32 + g * 8);
            acc = __builtin_amdgcn_mfma_f32_16x16x32_bf16(w, sf[kk], acc, 0, 0, 0);
        }
        f32x4 bb = *(const f32x4*)(b_ms + n2 * 16 + g * 4);
        union { __bf16 h[4]; uint2 u2; } p;
#pragma unroll
        for (int r = 0; r < 4; ++r) p.h[r] = (__bf16)prelu_f(acc[r] + bb[r], a_ms);
        const int row = j15 * 4 + (n2 >> 2);          // node j15, c = n2>>2
        const int d   = (n2 & 3) * 16 + g * 4;        // within-c feature
        *(uint2_a*)(Y + row * 128 + ((2 * d) ^ swzf(row))) = p.u2;
    }

    // ---- fused stage 1 + exchange + stage 3, per t (pipelined gathers) ----
#pragma unroll
    for (int t = 0; t < 4; ++t) {
        if (t < 3) {                                  // prefetch t+1 gathers
            const float* lsrc = last + ((size_t)((b * N_TOT + cl[t + 1]) * 4 + c)) * 64;
            const float* rsrc = last + ((size_t)((b * N_TOT + cr[t + 1]) * 4 + c)) * 64;
#pragma unroll
            for (int kk = 0; kk < 4; ++kk) {
                const float* src = (kk < 2 ? lsrc + kk * 32 : rsrc + (kk - 2) * 32) + g * 8;
                gr[(t + 1) & 1][2 * kk]     = *(const f32x4*)(src);
                gr[(t + 1) & 1][2 * kk + 1] = *(const f32x4*)(src + 4);
            }
        }

        bf16x8 xf[4];
#pragma unroll
        for (int kk = 0; kk < 4; ++kk) xf[kk] = cvt8(gr[t & 1][2 * kk], gr[t & 1][2 * kk + 1]);

        // stage-1 MFMA: lane (g,j15) produces ans chunk q=4n+g (4 feats) for row 16t+j15
        uint32_t pnx[4], pny[4];
#pragma unroll
        for (int n = 0; n < 4; ++n) {
            f32x4 acc = {0.f, 0.f, 0.f, 0.f};
#pragma unroll
            for (int kk = 0; kk < 4; ++kk) {
                bf16x8 w = *(const bf16x8*)(Wm_t + (n * 16 + j15) * 128 + kk * 32 + g * 8);
                acc = __builtin_amdgcn_mfma_f32_16x16x32_bf16(w, xf[kk], acc, 0, 0, 0);
            }
            f32x4 bm = *(const f32x4*)(b_merge + n * 16 + g * 4);
            union { __bf16 h[4]; uint32_t u[2]; } p;
#pragma unroll
            for (int r = 0; r < 4; ++r) p.h[r] = (__bf16)prelu_f(acc[r] + bm[r], a_merge);
            pnx[n] = p.u[0]; pny[n] = p.u[1];
        }

        // exchange ans across the 4 g-lanes (lane bits 4-5) via XOR shuffles:
        // dst g needs chunks {kk*8+2g, +1}: lo from g_src=2(g&1) (step d=(-g)&3),
        // hi from g_src=2(g&1)+1 (step d^1). src at step d exposes pn[2kk+((g^d)>>1)].
        const int dlo = (4 - g) & 3;
        const int dhi = dlo ^ 1;
        uint32_t lox[2], loy[2], hix[2], hiy[2];
#pragma unroll
        for (int d = 0; d < 4; ++d) {
            const int nsbit = ((g ^ d) >> 1) & 1;
#pragma unroll
            for (int kk = 0; kk < 2; ++kk) {
                uint32_t vx = nsbit ? pnx[2 * kk + 1] : pnx[2 * kk];
                uint32_t vy = nsbit ? pny[2 * kk + 1] : pny[2 * kk];
                uint32_t rx = d ? __shfl_xor(vx, d << 4, 64) : vx;
                uint32_t ry = d ? __shfl_xor(vy, d << 4, 64) : vy;
                if (d == 0) {
                    lox[kk] = rx; loy[kk] = ry; hix[kk] = rx; hiy[kk] = ry;
                } else {
                    lox[kk] = (dlo == d) ? rx : lox[kk];
                    loy[kk] = (dlo == d) ? ry : loy[kk];
                    hix[kk] = (dhi == d) ? rx : hix[kk];
                    hiy[kk] = (dhi == d) ? ry : hiy[kk];
                }
            }
        }
        union { uint32_t u[4]; bf16x8_a v; } yf0, yf1;
        yf0.u[0] = lox[0]; yf0.u[1] = loy[0]; yf0.u[2] = hix[0]; yf0.u[3] = hiy[0];
        yf1.u[0] = lox[1]; yf1.u[1] = loy[1]; yf1.u[2] = hix[1]; yf1.u[3] = hiy[1];

        // s' fragments from LDS
        const int row = t * 16 + j15;
        const int sz  = swzf(row);
        bf16x8 yf2 = *(const bf16x8_a*)(Y + row * 128 + ((16 * g) ^ sz));
        bf16x8 yf3 = *(const bf16x8_a*)(Y + row * 128 + ((64 + 16 * g) ^ sz));

        // stage 3: out = prelu([ans|s'] @ W_msamp + b_msamp)
        float* obase = out + ((size_t)((b * M_TOT + m_base + t * 4 + nl) * 4 + c)) * 64;
#pragma unroll
        for (int n = 0; n < 4; ++n) {
            f32x4 acc = {0.f, 0.f, 0.f, 0.f};
            bf16x8 w0 = *(const bf16x8*)(Wsa_t + (n * 16 + j15) * 128 + 0 * 32 + g * 8);
            bf16x8 w1 = *(const bf16x8*)(Wsa_t + (n * 16 + j15) * 128 + 1 * 32 + g * 8);
            bf16x8 w2 = *(const bf16x8*)(Wsa_t + (n * 16 + j15) * 128 + 2 * 32 + g * 8);
            bf16x8 w3 = *(const bf16x8*)(Wsa_t + (n * 16 + j15) * 128 + 3 * 32 + g * 8);
            acc = __builtin_amdgcn_mfma_f32_16x16x32_bf16(w0, yf0.v, acc, 0, 0, 0);
            acc = __builtin_amdgcn_mfma_f32_16x16x32_bf16(w1, yf1.v, acc, 0, 0, 0);
            acc = __builtin_amdgcn_mfma_f32_16x16x32_bf16(w2, yf2,   acc, 0, 0, 0);
            acc = __builtin_amdgcn_mfma_f32_16x16x32_bf16(w3, yf3,   acc, 0, 0, 0);
            f32x4 ba = *(const f32x4*)(b_msamp + n * 16 + g * 4);
            f32x4 o;
#pragma unroll
            for (int r = 0; r < 4; ++r) o[r] = prelu_f(acc[r] + ba[r], a_msamp);
            *(f32x4*)(obase + n * 16 + g * 4) = o;
        }
    }
}

extern "C" void kernel_launch(void* const* d_in, const int* in_sizes, int n_in,
                              void* d_out, int out_size, void* d_ws, size_t ws_size,
                              hipStream_t stream)
{
    const float* last    = (const float*)d_in[0];
    const float* sample  = (const float*)d_in[1];
    const int*   child_l = (const int*)d_in[2];
    const int*   child_r = (const int*)d_in[3];
    const int*   child_s = (const int*)d_in[4];
    const float* W_merge = (const float*)d_in[5];
    const float* b_merge = (const float*)d_in[6];
    const float* a_merge = (const float*)d_in[7];
    const float* W_ms    = (const float*)d_in[8];
    const float* b_ms    = (const float*)d_in[9];
    const float* a_ms    = (const float*)d_in[10];
    const float* W_msamp = (const float*)d_in[11];
    const float* b_msamp = (const float*)d_in[12];
    const float* a_msamp = (const float*)d_in[13];
    float* out = (float*)d_out;

    hipLaunchKernelGGL(prep_weights, dim3(192), dim3(256), 0, stream,
                       W_merge, W_ms, W_msamp, (__hip_bfloat16*)d_ws);

    hipLaunchKernelGGL(encoder_fused, dim3(2048), dim3(256), 0, stream,
                       last, sample, child_l, child_r, child_s,
                       (const __bf16*)d_ws,
                       b_merge, a_merge, b_ms, a_ms, b_msamp, a_msamp, out);
}

// Round 3
// 244.172 us; speedup vs baseline: 1.0165x; 1.0165x over previous
//
#include <hip/hip_runtime.h>
#include <hip/hip_bf16.h>

#define N_TOT 65536
#define M_TOT 32768

typedef __bf16 bf16x8 __attribute__((ext_vector_type(8)));
typedef float  f32x4  __attribute__((ext_vector_type(4)));
typedef bf16x8 bf16x8_a __attribute__((may_alias));
typedef uint2  uint2_a  __attribute__((may_alias));

__device__ __forceinline__ float prelu_f(float x, float a) { return x >= 0.f ? x : a * x; }
// swizzle: uniform bank spread for BOTH stage-2 writes (row=4*j15+c) and
// stage-3 reads (row=16t+j15). XORs LDS 16B-slot index with ((row^(row>>3))&7).
__device__ __forceinline__ int swzf(int row) { return ((row ^ (row >> 3)) & 7) << 4; }

__device__ __forceinline__ bf16x8 cvt8(f32x4 a, f32x4 b) {
    bf16x8 v;
    v[0] = (__bf16)a[0]; v[1] = (__bf16)a[1]; v[2] = (__bf16)a[2]; v[3] = (__bf16)a[3];
    v[4] = (__bf16)b[0]; v[5] = (__bf16)b[1]; v[6] = (__bf16)b[2]; v[7] = (__bf16)b[3];
    return v;
}

// d_ws layout (bf16): [0,8192) Wm_t[64][128]; [8192,40960) Wms_t[256][128];
// [40960,49152) Wsa_t[64][128].  W*_t[n][k] = W[k][n].
__global__ void prep_weights(const float* __restrict__ Wm,
                             const float* __restrict__ Wms,
                             const float* __restrict__ Wsa,
                             __hip_bfloat16* __restrict__ ws)
{
    int t = blockIdx.x * blockDim.x + threadIdx.x;
    if (t < 8192) {
        int n = t >> 7, k = t & 127;
        ws[t] = __float2bfloat16(Wm[k * 64 + n]);
    } else if (t < 40960) {
        int u = t - 8192; int n = u >> 7, k = u & 127;
        ws[t] = __float2bfloat16(Wms[k * 256 + n]);
    } else if (t < 49152) {
        int u = t - 40960; int n = u >> 7, k = u & 127;
        ws[t] = __float2bfloat16(Wsa[k * 64 + n]);
    }
}

// One wave = 16 nodes, fused stage1/2/3. s' exchanged via 8KB/wave LDS tile,
// ans exchanged via 4-lane XOR shuffles (no LDS). Swapped MFMA: D = W^T X^T.
// launch_bounds(256,2): 256-VGPR budget -> NO spills (256,4 spilled: R2 showed
// +74MB scratch writes at VGPR_Count=56). Natural ~110 VGPR -> 16 waves/CU.
__global__ __launch_bounds__(256, 2) void encoder_fused(
    const float* __restrict__ last,
    const float* __restrict__ sample,
    const int* __restrict__ child_l,
    const int* __restrict__ child_r,
    const int* __restrict__ child_s,
    const __bf16* __restrict__ wt,
    const float* __restrict__ b_merge, const float* __restrict__ a_merge_p,
    const float* __restrict__ b_ms,    const float* __restrict__ a_ms_p,
    const float* __restrict__ b_msamp, const float* __restrict__ a_msamp_p,
    float* __restrict__ out)
{
    __shared__ char lds_raw[4][8192];       // 32KB/block
    const int tid  = threadIdx.x;
    const int lane = tid & 63;
    const int wid  = tid >> 6;
    char* Y = &lds_raw[wid][0];             // wave-private [64 rows][128B]

    const int group  = blockIdx.x * 4 + wid;
    const int b      = group >> 11;
    const int m_base = (group & 2047) << 4;

    const int g   = lane >> 4;
    const int j15 = lane & 15;
    const int nl  = j15 >> 2;               // node-local (for stage1/3 rows)
    const int c   = j15 & 3;

    const float a_merge = *a_merge_p;
    const float a_ms    = *a_ms_p;
    const float a_msamp = *a_msamp_p;

    const __bf16* Wm_t  = wt;
    const __bf16* Wms_t = wt + 8192;
    const __bf16* Wsa_t = wt + 40960;

    // ---- index loads (all upfront) ----
    int cl[4], cr[4];
#pragma unroll
    for (int t = 0; t < 4; ++t) {
        cl[t] = child_l[m_base + t * 4 + nl];
        cr[t] = child_r[m_base + t * 4 + nl];
    }
    const int cs = child_s[m_base + j15];

    // ---- stage-2 sample loads (issue early) ----
    const float* ssrc = sample + ((size_t)(b * N_TOT + cs)) * 128;
    f32x4 sr[8];
#pragma unroll
    for (int kk = 0; kk < 4; ++kk) {
        sr[2 * kk]     = *(const f32x4*)(ssrc + kk * 32 + g * 8);
        sr[2 * kk + 1] = *(const f32x4*)(ssrc + kk * 32 + g * 8 + 4);
    }

    // ---- t=0 gather issue (in flight during stage-2 compute) ----
    f32x4 gr[2][8];
    {
        const float* lsrc = last + ((size_t)((b * N_TOT + cl[0]) * 4 + c)) * 64;
        const float* rsrc = last + ((size_t)((b * N_TOT + cr[0]) * 4 + c)) * 64;
#pragma unroll
        for (int kk = 0; kk < 4; ++kk) {
            const float* src = (kk < 2 ? lsrc + kk * 32 : rsrc + (kk - 2) * 32) + g * 8;
            gr[0][2 * kk]     = *(const f32x4*)(src);
            gr[0][2 * kk + 1] = *(const f32x4*)(src + 4);
        }
    }

    // ---- stage 2: s' = prelu(s @ W_ms + b_ms) -> LDS ----
    bf16x8 sf[4];
#pragma unroll
    for (int kk = 0; kk < 4; ++kk) sf[kk] = cvt8(sr[2 * kk], sr[2 * kk + 1]);
#pragma unroll
    for (int n2 = 0; n2 < 16; ++n2) {
        f32x4 acc = {0.f, 0.f, 0.f, 0.f};
#pragma unroll
        for (int kk = 0; kk < 4; ++kk) {
            bf16x8 w = *(const bf16x8*)(Wms_t + (n2 * 16 + j15) * 128 + kk * 32 + g * 8);
            acc = __builtin_amdgcn_mfma_f32_16x16x32_bf16(w, sf[kk], acc, 0, 0, 0);
        }
        f32x4 bb = *(const f32x4*)(b_ms + n2 * 16 + g * 4);
        union { __bf16 h[4]; uint2 u2; } p;
#pragma unroll
        for (int r = 0; r < 4; ++r) p.h[r] = (__bf16)prelu_f(acc[r] + bb[r], a_ms);
        const int row = j15 * 4 + (n2 >> 2);          // node j15, c = n2>>2
        const int d   = (n2 & 3) * 16 + g * 4;        // within-c feature
        *(uint2_a*)(Y + row * 128 + ((2 * d) ^ swzf(row))) = p.u2;
    }

    // ---- fused stage 1 + exchange + stage 3, per t (pipelined gathers) ----
#pragma unroll
    for (int t = 0; t < 4; ++t) {
        if (t < 3) {                                  // prefetch t+1 gathers
            const float* lsrc = last + ((size_t)((b * N_TOT + cl[t + 1]) * 4 + c)) * 64;
            const float* rsrc = last + ((size_t)((b * N_TOT + cr[t + 1]) * 4 + c)) * 64;
#pragma unroll
            for (int kk = 0; kk < 4; ++kk) {
                const float* src = (kk < 2 ? lsrc + kk * 32 : rsrc + (kk - 2) * 32) + g * 8;
                gr[(t + 1) & 1][2 * kk]     = *(const f32x4*)(src);
                gr[(t + 1) & 1][2 * kk + 1] = *(const f32x4*)(src + 4);
            }
        }

        bf16x8 xf[4];
#pragma unroll
        for (int kk = 0; kk < 4; ++kk) xf[kk] = cvt8(gr[t & 1][2 * kk], gr[t & 1][2 * kk + 1]);

        // stage-1 MFMA: lane (g,j15) produces ans chunk q=4n+g (4 feats) for row 16t+j15
        uint32_t pnx[4], pny[4];
#pragma unroll
        for (int n = 0; n < 4; ++n) {
            f32x4 acc = {0.f, 0.f, 0.f, 0.f};
#pragma unroll
            for (int kk = 0; kk < 4; ++kk) {
                bf16x8 w = *(const bf16x8*)(Wm_t + (n * 16 + j15) * 128 + kk * 32 + g * 8);
                acc = __builtin_amdgcn_mfma_f32_16x16x32_bf16(w, xf[kk], acc, 0, 0, 0);
            }
            f32x4 bm = *(const f32x4*)(b_merge + n * 16 + g * 4);
            union { __bf16 h[4]; uint32_t u[2]; } p;
#pragma unroll
            for (int r = 0; r < 4; ++r) p.h[r] = (__bf16)prelu_f(acc[r] + bm[r], a_merge);
            pnx[n] = p.u[0]; pny[n] = p.u[1];
        }

        // exchange ans across the 4 g-lanes (lane bits 4-5) via XOR shuffles
        const int dlo = (4 - g) & 3;
        const int dhi = dlo ^ 1;
        uint32_t lox[2], loy[2], hix[2], hiy[2];
#pragma unroll
        for (int d = 0; d < 4; ++d) {
            const int nsbit = ((g ^ d) >> 1) & 1;
#pragma unroll
            for (int kk = 0; kk < 2; ++kk) {
                uint32_t vx = nsbit ? pnx[2 * kk + 1] : pnx[2 * kk];
                uint32_t vy = nsbit ? pny[2 * kk + 1] : pny[2 * kk];
                uint32_t rx = d ? __shfl_xor(vx, d << 4, 64) : vx;
                uint32_t ry = d ? __shfl_xor(vy, d << 4, 64) : vy;
                if (d == 0) {
                    lox[kk] = rx; loy[kk] = ry; hix[kk] = rx; hiy[kk] = ry;
                } else {
                    lox[kk] = (dlo == d) ? rx : lox[kk];
                    loy[kk] = (dlo == d) ? ry : loy[kk];
                    hix[kk] = (dhi == d) ? rx : hix[kk];
                    hiy[kk] = (dhi == d) ? ry : hiy[kk];
                }
            }
        }
        union { uint32_t u[4]; bf16x8_a v; } yf0, yf1;
        yf0.u[0] = lox[0]; yf0.u[1] = loy[0]; yf0.u[2] = hix[0]; yf0.u[3] = hiy[0];
        yf1.u[0] = lox[1]; yf1.u[1] = loy[1]; yf1.u[2] = hix[1]; yf1.u[3] = hiy[1];

        // s' fragments from LDS
        const int row = t * 16 + j15;
        const int sz  = swzf(row);
        bf16x8 yf2 = *(const bf16x8_a*)(Y + row * 128 + ((16 * g) ^ sz));
        bf16x8 yf3 = *(const bf16x8_a*)(Y + row * 128 + ((64 + 16 * g) ^ sz));

        // stage 3: out = prelu([ans|s'] @ W_msamp + b_msamp)
        float* obase = out + ((size_t)((b * M_TOT + m_base + t * 4 + nl) * 4 + c)) * 64;
#pragma unroll
        for (int n = 0; n < 4; ++n) {
            f32x4 acc = {0.f, 0.f, 0.f, 0.f};
            bf16x8 w0 = *(const bf16x8*)(Wsa_t + (n * 16 + j15) * 128 + 0 * 32 + g * 8);
            bf16x8 w1 = *(const bf16x8*)(Wsa_t + (n * 16 + j15) * 128 + 1 * 32 + g * 8);
            bf16x8 w2 = *(const bf16x8*)(Wsa_t + (n * 16 + j15) * 128 + 2 * 32 + g * 8);
            bf16x8 w3 = *(const bf16x8*)(Wsa_t + (n * 16 + j15) * 128 + 3 * 32 + g * 8);
            acc = __builtin_amdgcn_mfma_f32_16x16x32_bf16(w0, yf0.v, acc, 0, 0, 0);
            acc = __builtin_amdgcn_mfma_f32_16x16x32_bf16(w1, yf1.v, acc, 0, 0, 0);
            acc = __builtin_amdgcn_mfma_f32_16x16x32_bf16(w2, yf2,   acc, 0, 0, 0);
            acc = __builtin_amdgcn_mfma_f32_16x16x32_bf16(w3, yf3,   acc, 0, 0, 0);
            f32x4 ba = *(const f32x4*)(b_msamp + n * 16 + g * 4);
            f32x4 o;
#pragma unroll
            for (int r = 0; r < 4; ++r) o[r] = prelu_f(acc[r] + ba[r], a_msamp);
            // streamed output, never re-read: non-temporal to keep L2/L3 for gathers
            __builtin_nontemporal_store(o, (f32x4*)(obase + n * 16 + g * 4));
        }
    }
}

extern "C" void kernel_launch(void* const* d_in, const int* in_sizes, int n_in,
                              void* d_out, int out_size, void* d_ws, size_t ws_size,
                              hipStream_t stream)
{
    const float* last    = (const float*)d_in[0];
    const float* sample  = (const float*)d_in[1];
    const int*   child_l = (const int*)d_in[2];
    const int*   child_r = (const int*)d_in[3];
    const int*   child_s = (const int*)d_in[4];
    const float* W_merge = (const float*)d_in[5];
    const float* b_merge = (const float*)d_in[6];
    const float* a_merge = (const float*)d_in[7];
    const float* W_ms    = (const float*)d_in[8];
    const float* b_ms    = (const float*)d_in[9];
    const float* a_ms    = (const float*)d_in[10];
    const float* W_msamp = (const float*)d_in[11];
    const float* b_msamp = (const float*)d_in[12];
    const float* a_msamp = (const float*)d_in[13];
    float* out = (float*)d_out;

    hipLaunchKernelGGL(prep_weights, dim3(192), dim3(256), 0, stream,
                       W_merge, W_ms, W_msamp, (__hip_bfloat16*)d_ws);

    hipLaunchKernelGGL(encoder_fused, dim3(2048), dim3(256), 0, stream,
                       last, sample, child_l, child_r, child_s,
                       (const __bf16*)d_ws,
                       b_merge, a_merge, b_ms, a_ms, b_msamp, a_msamp, out);
}